// Round 9
// baseline (10124.577 us; speedup 1.0000x reference)
//
#include <hip/hip_runtime.h>
#include <cstdint>
#include <cstddef>

#define B_ 64
#define T_ 1024
#define D_ 1024
#define NBLK 256

typedef __attribute__((ext_vector_type(8))) _Float16 half8;
typedef __attribute__((ext_vector_type(4))) float f32x4;
typedef unsigned int u32;
typedef unsigned long long u64;
typedef unsigned short u16;

static __device__ __forceinline__ f32x4 mfma16(half8 a, half8 b, f32x4 c) {
  return __builtin_amdgcn_mfma_f32_16x16x32_f16(a, b, c, 0, 0, 0);
}
static __device__ __forceinline__ u32 cohl32(const u32* p) {
  return __hip_atomic_load(p, __ATOMIC_RELAXED, __HIP_MEMORY_SCOPE_AGENT);
}
static __device__ __forceinline__ void cohs32(u32* p, u32 v) {
  __hip_atomic_store(p, v, __ATOMIC_RELAXED, __HIP_MEMORY_SCOPE_AGENT);
}
static __device__ __forceinline__ void cohs64(u64* p, u64 v) {
  __hip_atomic_store(p, v, __ATOMIC_RELAXED, __HIP_MEMORY_SCOPE_AGENT);
}
static __device__ __forceinline__ u16 h2u(_Float16 h) {
  return __builtin_bit_cast(u16, h);
}

// ---- staging: 32 rows x 1024 fp16 -> regs -> LDS (XOR-swizzled) ----------
// thread t: row r=t>>5, lane j=t&31; covers bytes j*16 + k*512 (k=0..3).

// plain cached fp16 load, row stride = T*D (x history)
static __device__ __forceinline__ void stage_x(const _Float16* src, u64* st, int tid) {
  const int r = tid >> 5, j = tid & 31;
  const u64* p = (const u64*)(src + (size_t)r * T_ * D_) + j * 2;
  #pragma unroll
  for (int k = 0; k < 4; ++k) {
    st[2 * k] = p[k * 64];
    st[2 * k + 1] = p[k * 64 + 1];
  }
}

// plain cached fp16 load, row stride = D (h0 history slab [B][D])
static __device__ __forceinline__ void stage_h(const _Float16* src, u64* st, int tid) {
  const int r = tid >> 5, j = tid & 31;
  const u64* p = (const u64*)(src + (size_t)r * D_) + j * 2;
  #pragma unroll
  for (int k = 0; k < 4; ++k) {
    st[2 * k] = p[k * 64];
    st[2 * k + 1] = p[k * 64 + 1];
  }
}

// plain cached f32 load + cvt fp16, row stride = T*D (x fallback / out history)
static __device__ __forceinline__ void stage_xf(const float* src, u64* st, int tid) {
  const int r = tid >> 5, j = tid & 31;
  const float4* p = (const float4*)(src + (size_t)r * T_ * D_) + j * 2;
  #pragma unroll
  for (int k = 0; k < 4; ++k) {
    #pragma unroll
    for (int q = 0; q < 2; ++q) {
      float4 v = p[k * 64 + q];
      union { u16 us[4]; u64 u; } pk;
      pk.us[0] = h2u((_Float16)v.x); pk.us[1] = h2u((_Float16)v.y);
      pk.us[2] = h2u((_Float16)v.z); pk.us[3] = h2u((_Float16)v.w);
      st[2 * k + q] = pk.u;
    }
  }
}

static __device__ __forceinline__ void stage_write(char* lds, const u64* st, int tid) {
  const int r = tid >> 5, j = tid & 31;
  const int sw = (r & 7) << 4;
  char* row = lds + r * 2048;
  #pragma unroll
  for (int k = 0; k < 4; ++k) {
    char* dst = row + ((j * 16 + k * 512) ^ sw);
    *(u64*)dst = st[2 * k];
    *(u64*)(dst + 8) = st[2 * k + 1];
  }
}

// ---- GEMM: weights from registers (preloaded, pinned via opaque asm) -----
static __device__ __forceinline__ void gemm_reg(
    f32x4* acc, const char* ldsA, const half8* w, int kq, int lane) {
  const int r = lane & 15;
  const int kl2 = (lane >> 4) << 4;
  const int sw = (r & 7) << 4;
  const char* p0 = ldsA + r * 2048;
  const char* p1 = ldsA + (16 + r) * 2048;   // (16+r)&7 == r&7 -> same swizzle
  #pragma unroll
  for (int ks = 0; ks < 8; ++ks) {
    const int kb = (kq * 512 + ks * 64 + kl2) ^ sw;
    half8 a0 = *(const half8*)(p0 + kb);
    half8 a1 = *(const half8*)(p1 + kb);
    acc[0] = mfma16(a0, w[ks], acc[0]);
    acc[1] = mfma16(a1, w[ks], acc[1]);
  }
}

// one wave polls all 256 arrival slots; trailing syncthreads releases block.
// Spin is BOUNDED: a would-be deadlock degrades to wrong results (absmax
// diagnosis) instead of a wedged GPU/dead container.
static __device__ __forceinline__ void pollwait(const u32* slots, u32 gen, int tid) {
  if (gen > 0 && tid < 64) {
    const u32* p = slots + tid * 32;
    int spin = 0;
    while ((cohl32(p) < gen || cohl32(p + 64 * 32) < gen ||
            cohl32(p + 128 * 32) < gen || cohl32(p + 192 * 32) < gen) &&
           ++spin < (1 << 26))
      __builtin_amdgcn_s_sleep(1);
  }
  __syncthreads();
}

// ---- persistent kernel ---------------------------------------------------
// 256 blocks x 1024 threads. xcd=bid&7, slot=bid>>3:
//   lyr=slot>>4, mh=(slot>>3)&1, dgrp=xcd*8+(slot&7).
// Block: layer lyr, batch rows mbase..+32, dims d0..+16 (4 gates), K=1024.
// 16 waves = (kq 0..3)x(gate 0..3); wave: 2 m-tiles, weights in 64 regs.
// Super-step s: lyr0 does t=s, lyr1 does t=s-1.
// h state: write-once history buffers, sc1 store / plain cached load.
//   h0hist[t][B][D] fp16;  h1 history = out[B][T][D] f32 (sc1-stored).
// Barrier: poll(gen s) at point-of-use, arrive(s+1) at end. Max skew 1 step;
// write-once buffers make skew harmless (no WAR).

template <bool XPRE>
__global__ __launch_bounds__(1024, 4) void lstm_persist(
    const float* __restrict__ x32, const _Float16* __restrict__ xh,
    const _Float16* __restrict__ W,
    _Float16* __restrict__ h0hist, float* __restrict__ out, u32* slots)
{
  __shared__ char ldsA[32 * 2048];
  __shared__ float glp[4][32][68];
  const int tid = threadIdx.x;
  const int lane = tid & 63;
  const int wv = tid >> 6;
  const int kq = wv >> 2;
  const int nt = wv & 3;                   // gate (i,f,g,o)
  const int bid = blockIdx.x;
  const int slot = bid >> 3;
  const int lyr = slot >> 4;
  const int mh = (slot >> 3) & 1;
  const int dgrp = (bid & 7) * 8 + (slot & 7);
  const int d0 = dgrp << 4;
  const int mbase = mh << 5;

  // ---- weight preload: 8+8 half8 fragments per lane ----
  const _Float16* Wih = W + (size_t)(2 * lyr) * 4096 * 1024;
  const _Float16* Whh = Wih + (size_t)4096 * 1024;
  const size_t wrow = (size_t)(nt * 1024 + d0 + (lane & 15)) * 1024;
  const int kl2 = (lane >> 4) << 4;
  half8 wih[8], whh[8];
  #pragma unroll
  for (int ks = 0; ks < 8; ++ks) {
    const int kb = kq * 512 + ks * 64 + kl2;       // byte offset in row
    wih[ks] = *(const half8*)(Wih + wrow + (kb >> 1));
    whh[ks] = *(const half8*)(Whh + wrow + (kb >> 1));
  }
  #pragma unroll
  for (int ks = 0; ks < 8; ++ks) {       // pin: cannot be rematerialized
    asm volatile("" : "+v"(wih[ks]));
    asm volatile("" : "+v"(whh[ks]));
  }

  float creg0 = 0.f, creg1 = 0.f;        // cell state in registers
  const int cb = tid >> 3;
  const int cd = (tid & 7) << 1;

  u64 st[8];
  if (lyr == 0) {                        // prefetch x for s=0
    if (XPRE) stage_x(xh + (size_t)mbase * T_ * D_, st, tid);
    else      stage_xf(x32 + (size_t)mbase * T_ * D_, st, tid);
  }

  for (int s = 0; s <= T_; ++s) {
    const bool active = lyr ? (s >= 1) : (s < T_);
    const int t = lyr ? (s - 1) : s;

    if (active) {
      f32x4 acc[2];
      acc[0] = (f32x4){0.f, 0.f, 0.f, 0.f};
      acc[1] = (f32x4){0.f, 0.f, 0.f, 0.f};

      if (lyr == 0) {
        // x GEMM is barrier-independent: run it under the barrier skew
        stage_write(ldsA, st, tid);
        __syncthreads();
        gemm_reg(acc, ldsA, wih, kq, lane);
        pollwait(slots, (u32)s, tid);          // also fences ldsA reuse
        if (s > 0) {
          stage_h(h0hist + ((size_t)(s - 1) * B_ + mbase) * D_, st, tid);
          stage_write(ldsA, st, tid);
          __syncthreads();
          gemm_reg(acc, ldsA, whh, kq, lane);
        }
      } else {
        pollwait(slots, (u32)s, tid);
        stage_h(h0hist + ((size_t)t * B_ + mbase) * D_, st, tid);
        stage_write(ldsA, st, tid);
        __syncthreads();
        if (t > 0)                              // out@t-1 loads overlap gemm1
          stage_xf(out + ((size_t)mbase * T_ + (t - 1)) * D_, st, tid);
        gemm_reg(acc, ldsA, wih, kq, lane);
        __syncthreads();
        if (t > 0) {
          stage_write(ldsA, st, tid);
          __syncthreads();
          gemm_reg(acc, ldsA, whh, kq, lane);
        }
      }

      // kq partials -> LDS
      const int r4 = (lane >> 4) << 2;
      const int ccol = nt * 16 + (lane & 15);
      #pragma unroll
      for (int mt = 0; mt < 2; ++mt)
        #pragma unroll
        for (int i = 0; i < 4; ++i)
          glp[kq][mt * 16 + r4 + i][ccol] = acc[mt][i];
      __syncthreads();

      if (tid < 256) {
        float g4[4][2];
        #pragma unroll
        for (int gg = 0; gg < 4; ++gg) {
          g4[gg][0] = glp[0][cb][gg * 16 + cd] + glp[1][cb][gg * 16 + cd]
                    + glp[2][cb][gg * 16 + cd] + glp[3][cb][gg * 16 + cd];
          g4[gg][1] = glp[0][cb][gg * 16 + cd + 1] + glp[1][cb][gg * 16 + cd + 1]
                    + glp[2][cb][gg * 16 + cd + 1] + glp[3][cb][gg * 16 + cd + 1];
        }
        const float i0 = 1.f / (1.f + expf(-g4[0][0])), i1 = 1.f / (1.f + expf(-g4[0][1]));
        const float f0 = 1.f / (1.f + expf(-g4[1][0])), f1 = 1.f / (1.f + expf(-g4[1][1]));
        const float z0 = tanhf(g4[2][0]),               z1 = tanhf(g4[2][1]);
        const float o0 = 1.f / (1.f + expf(-g4[3][0])), o1 = 1.f / (1.f + expf(-g4[3][1]));
        creg0 = f0 * creg0 + i0 * z0;
        creg1 = f1 * creg1 + i1 * z1;
        const float hn0 = o0 * tanhf(creg0);
        const float hn1 = o1 * tanhf(creg1);
        if (lyr == 0) {
          union { u16 us[2]; u32 u; } pk;
          pk.us[0] = h2u((_Float16)hn0);
          pk.us[1] = h2u((_Float16)hn1);
          cohs32((u32*)(h0hist + ((size_t)t * B_ + mbase + cb) * D_ + d0 + cd), pk.u);
        } else {
          union { float f[2]; u64 u; } po;
          po.f[0] = hn0; po.f[1] = hn1;
          cohs64((u64*)(out + ((size_t)(mbase + cb) * T_ + t) * D_ + d0 + cd), po.u);
        }
      }
    }

    // drain all sc1 stores (syncthreads emits vmcnt(0) per wave), then arrive
    __syncthreads();
    if (tid == 0) cohs32(slots + bid * 32, (u32)(s + 1));

    // prefetch next x under other blocks' arrival window
    if (lyr == 0 && s + 1 < T_) {
      if (XPRE) stage_x(xh + ((size_t)mbase * T_ + (s + 1)) * D_, st, tid);
      else      stage_xf(x32 + ((size_t)mbase * T_ + (s + 1)) * D_, st, tid);
    }
  }
}

// ---- setup ---------------------------------------------------------------

__global__ void convw(const float* __restrict__ w0, const float* __restrict__ w1,
                      const float* __restrict__ w2, const float* __restrict__ w3,
                      u64* __restrict__ dst) {
  const size_t n1 = (size_t)D_ * D_;          // float4 count per matrix
  const size_t n = 4 * n1;
  for (size_t i = (size_t)blockIdx.x * blockDim.x + threadIdx.x; i < n;
       i += (size_t)gridDim.x * blockDim.x) {
    const size_t m = i / n1, j = i - m * n1;
    const float* src = (m == 0) ? w0 : (m == 1) ? w1 : (m == 2) ? w2 : w3;
    float4 v = ((const float4*)src)[j];
    union { u16 us[4]; u64 u; } pk;
    pk.us[0] = h2u((_Float16)v.x); pk.us[1] = h2u((_Float16)v.y);
    pk.us[2] = h2u((_Float16)v.z); pk.us[3] = h2u((_Float16)v.w);
    dst[i] = pk.u;
  }
}

__global__ void convx(const float* __restrict__ x, u64* __restrict__ xh) {
  const size_t n = (size_t)B_ * T_ * D_ / 4;
  for (size_t i = (size_t)blockIdx.x * blockDim.x + threadIdx.x; i < n;
       i += (size_t)gridDim.x * blockDim.x) {
    float4 v = ((const float4*)x)[i];
    union { u16 us[4]; u64 u; } pk;
    pk.us[0] = h2u((_Float16)v.x); pk.us[1] = h2u((_Float16)v.y);
    pk.us[2] = h2u((_Float16)v.z); pk.us[3] = h2u((_Float16)v.w);
    xh[i] = pk.u;
  }
}

// ---- host ----------------------------------------------------------------

extern "C" void kernel_launch(void* const* d_in, const int* in_sizes, int n_in,
                              void* d_out, int out_size, void* d_ws, size_t ws_size,
                              hipStream_t stream) {
  (void)in_sizes; (void)n_in; (void)out_size;
  const float* x = (const float*)d_in[0];
  const float* Wih0 = (const float*)d_in[1];
  const float* Whh0 = (const float*)d_in[2];
  const float* Wih1 = (const float*)d_in[3];
  const float* Whh1 = (const float*)d_in[4];
  float* out = (float*)d_out;

  char* ws = (char*)d_ws;
  const size_t MB = 1ull << 20;
  const size_t xbytes = (size_t)B_ * T_ * D_ * 2;    // 128MB
  // layout: [0,32MB) W fp16; 32MB: slots 32KB; 33MB: xh 128MB; 161MB: h0hist 128MB
  _Float16* Wf = (_Float16*)ws;
  u32* slots = (u32*)(ws + 32 * MB);
  _Float16* xh = (_Float16*)(ws + 33 * MB);
  const bool xpre = ws_size >= 33 * MB + 2 * xbytes;
  _Float16* h0hist = (_Float16*)(xpre ? (ws + 33 * MB + xbytes) : (ws + 33 * MB));

  hipMemsetAsync(slots, 0, 32768, stream);
  convw<<<4096, 256, 0, stream>>>(Wih0, Whh0, Wih1, Whh1, (u64*)Wf);
  if (xpre) {
    convx<<<4096, 256, 0, stream>>>(x, (u64*)xh);
    lstm_persist<true><<<NBLK, 1024, 0, stream>>>(x, xh, Wf, h0hist, out, slots);
  } else {
    lstm_persist<false><<<NBLK, 1024, 0, stream>>>(x, xh, Wf, h0hist, out, slots);
  }
}